// Round 1
// baseline (577.022 us; speedup 1.0000x reference)
//
#include <hip/hip_runtime.h>

typedef __attribute__((ext_vector_type(4))) float f32x4;
typedef __attribute__((ext_vector_type(8))) __bf16 bf16x8;
typedef __attribute__((ext_vector_type(4))) float f32x4v;

#define BM 128
#define BK 64
#define TOTALW 4096

struct Args {
  const float* x;
  const float* W[8];
  float* out;
};

__device__ __forceinline__ bf16x8 cvt8(f32x4 a, f32x4 b) {
  bf16x8 r;
  r[0] = (__bf16)a.x; r[1] = (__bf16)a.y; r[2] = (__bf16)a.z; r[3] = (__bf16)a.w;
  r[4] = (__bf16)b.x; r[5] = (__bf16)b.y; r[6] = (__bf16)b.z; r[7] = (__bf16)b.w;
  return r;
}

__global__ __launch_bounds__(256, 2) void ielin_kernel(Args args) {
  // bf16 LDS tiles, XOR-swizzled (16B granularity) to kill ds_read_b128 bank conflicts
  __shared__ __align__(16) ushort As[BM * BK];
  __shared__ __align__(16) ushort Bs[BM * BK];

  const int tid = threadIdx.x;
  const int bid = blockIdx.x;
  // XCD-aware bijective swizzle (8192 % 8 == 0): each XCD gets a contiguous chunk
  // of work-ids; the 32 column-tiles of one m-tile are consecutive on ONE XCD so
  // the 2MB fp32 A-panel stays L2-resident.
  const int work = (bid & 7) * 1024 + (bid >> 3);
  const int mt = work >> 5;   // m-tile 0..255
  const int c  = work & 31;   // 128-wide column tile 0..31

  // column tile -> block l (uniform scalar math, no tables)
  const int l = (c >= 1) + (c >= 2) + (c >= 5) + (c >= 8) + (c >= 13) + (c >= 18) + (c >= 25);
  const int pp = l >> 1, qq = l & 1;
  const int nirr = l | 1;                    // width_l / 128 = {1,1,3,3,5,5,7,7}
  const int cstart = 2 * pp * pp + qq * nirr;
  const int w  = nirr << 7;                  // K for this block
  const int sK = cstart << 7;                // column start of block in x/out
  const int noff = (c - cstart) << 7;        // row offset into W_l
  const float* __restrict__ Wl = args.W[l];

  // ---- staging coords: 256 threads, each owns 8 consecutive k per group, 4 groups per tile
  const int srow = tid >> 3;                 // 0..31
  const int sk   = (tid & 7) << 3;           // 0..56
  const float* ap = args.x + (size_t)(mt * BM + srow) * TOTALW + sK + sk;
  const float* bp = Wl + (size_t)(noff + srow) * w + sk;
  const size_t aStep = (size_t)32 * TOTALW;
  const size_t bStep = (size_t)32 * w;

  // ---- compute coords: 2x2 waves of 64x64, 4x4 fragments of 16x16x32
  const int lane = tid & 63;
  const int wid  = tid >> 6;
  const int wr = (wid >> 1) << 6;
  const int wc = (wid & 1) << 6;
  const int fr = lane & 15;                  // A-row / B-col within fragment
  const int kq = lane >> 4;                  // k-chunk of 8

  f32x4v acc[4][4] = {};

  f32x4 av[4][2], bv[4][2];
  const int nk = w >> 6;                     // 2..14 K-steps

  // prologue: load tile 0 into regs
  {
    const float* a = ap; const float* b = bp;
#pragma unroll
    for (int i = 0; i < 4; ++i) {
      av[i][0] = *(const f32x4*)(a); av[i][1] = *(const f32x4*)(a + 4); a += aStep;
      bv[i][0] = *(const f32x4*)(b); bv[i][1] = *(const f32x4*)(b + 4); b += bStep;
    }
  }

  for (int kt = 0; kt < nk; ++kt) {
    // convert + write current tile to LDS (swizzled)
#pragma unroll
    for (int i = 0; i < 4; ++i) {
      const int row = srow + 32 * i;
      const int e = (row * BK + sk) ^ ((row & 7) << 3);
      *(bf16x8*)&As[e] = cvt8(av[i][0], av[i][1]);
      *(bf16x8*)&Bs[e] = cvt8(bv[i][0], bv[i][1]);
    }
    __syncthreads();

    // issue next tile's global loads BEFORE compute so HBM latency hides under MFMA
    if (kt + 1 < nk) {
      const float* a = ap + (kt + 1) * BK;
      const float* b = bp + (kt + 1) * BK;
#pragma unroll
      for (int i = 0; i < 4; ++i) {
        av[i][0] = *(const f32x4*)(a); av[i][1] = *(const f32x4*)(a + 4); a += aStep;
        bv[i][0] = *(const f32x4*)(b); bv[i][1] = *(const f32x4*)(b + 4); b += bStep;
      }
    }

#pragma unroll
    for (int kk = 0; kk < 2; ++kk) {
      const int kb = kk * 32 + kq * 8;
      bf16x8 afr[4], bfr[4];
#pragma unroll
      for (int i = 0; i < 4; ++i) {
        const int ra = wr + i * 16 + fr;
        afr[i] = *(const bf16x8*)&As[(ra * BK + kb) ^ ((fr & 7) << 3)];
        const int rb = wc + i * 16 + fr;
        bfr[i] = *(const bf16x8*)&Bs[(rb * BK + kb) ^ ((fr & 7) << 3)];
      }
#pragma unroll
      for (int mi = 0; mi < 4; ++mi)
#pragma unroll
        for (int ni = 0; ni < 4; ++ni)
          acc[mi][ni] = __builtin_amdgcn_mfma_f32_16x16x32_bf16(afr[mi], bfr[ni], acc[mi][ni], 0, 0, 0);
    }
    __syncthreads();
  }

  // epilogue: C/D layout col=lane&15, row=(lane>>4)*4+reg  [m89-verified]
  float* op = args.out + (size_t)(mt * BM + wr + kq * 4) * TOTALW + (c << 7) + wc + fr;
#pragma unroll
  for (int mi = 0; mi < 4; ++mi) {
#pragma unroll
    for (int ni = 0; ni < 4; ++ni) {
      float* p = op + (size_t)(mi * 16) * TOTALW + ni * 16;
      p[0 * TOTALW] = acc[mi][ni][0];
      p[1 * TOTALW] = acc[mi][ni][1];
      p[2 * TOTALW] = acc[mi][ni][2];
      p[3 * TOTALW] = acc[mi][ni][3];
    }
  }
}

extern "C" void kernel_launch(void* const* d_in, const int* in_sizes, int n_in,
                              void* d_out, int out_size, void* d_ws, size_t ws_size,
                              hipStream_t stream) {
  Args args;
  args.x = (const float*)d_in[0];
  for (int i = 0; i < 8; ++i) args.W[i] = (const float*)d_in[1 + i];
  args.out = (float*)d_out;
  ielin_kernel<<<8192, 256, 0, stream>>>(args);
}